// Round 3
// baseline (107.155 us; speedup 1.0000x reference)
//
#include <hip/hip_runtime.h>
#include <hip/hip_bf16.h>

// B=1024, IN=768, HID=512, OUT=256. Two dispatches:
//  K1 gemm_ct : c = combin@W2^T+b2 (K=768), t = s_emb@W1^T+b1 (K=512)
//               32x32 tile/block, 4-wave K-split, depth-2 global prefetch,
//               parallel cross-wave reduce tail. 1024 blocks.
//  K2 attn_out: per block (32 rows x 32 out-cols): Taylor moments + Horner
//               (recomputed per col-tile, cheap VALU) -> o2 bf16 in LDS
//               (XOR-swizzled) -> 32x32 MFMA GEMM vs W3, 8-wave K-split.
//               256 blocks x 512 thr. Removes a launch + o2 HBM round-trip.

#define B_SZ 1024
#define HID 512
#define IN_D 768
#define OUT_D 256
#define NK 8

typedef float floatx16 __attribute__((ext_vector_type(16)));
typedef short short8  __attribute__((ext_vector_type(8)));

// round-half-up fp32->bf16 pair pack (low16 = a, high16 = b)
__device__ __forceinline__ unsigned pack_bf16(float a, float b) {
    unsigned ua = __float_as_uint(a) + 0x8000u;
    unsigned ub = __float_as_uint(b) + 0x8000u;
    return __builtin_amdgcn_perm(ub, ua, 0x07060302);
}
__device__ __forceinline__ uint4 pack8(float4 lo, float4 hi) {
    uint4 v;
    v.x = pack_bf16(lo.x, lo.y); v.y = pack_bf16(lo.z, lo.w);
    v.z = pack_bf16(hi.x, hi.y); v.w = pack_bf16(hi.z, hi.w);
    return v;
}

// One 32x32 C tile per block; 4 waves split K (NCH 16-wide chunks each).
// Fragments loaded directly from global in fragment order; depth-2 prefetch.
template<int NCH>
__device__ __forceinline__ void gemm32_f32(
    const float* __restrict__ A, const float* __restrict__ W,
    const float* __restrict__ bias, float* __restrict__ C,
    int N, int K, int row0, int col0, float (*__restrict__ redf)[64])
{
    const int tid  = threadIdx.x;
    const int w    = tid >> 6;
    const int lane = tid & 63;
    const int m    = lane & 31;
    const int kh   = lane >> 5;
    const int k0   = w * NCH * 16 + kh * 8;

    const float* pa = A + (size_t)(row0 + m) * K + k0;
    const float* pw = W + (size_t)(col0 + m) * K + k0;

    float4 a0[2], a1[2], b0[2], b1[2];
    a0[0] = *(const float4*)pa;        a1[0] = *(const float4*)(pa + 4);
    b0[0] = *(const float4*)pw;        b1[0] = *(const float4*)(pw + 4);
    a0[1] = *(const float4*)(pa + 16); a1[1] = *(const float4*)(pa + 20);
    b0[1] = *(const float4*)(pw + 16); b1[1] = *(const float4*)(pw + 20);

    floatx16 acc = {};
    #pragma unroll
    for (int c = 0; c < NCH; ++c) {
        const int s = c & 1;                 // compile-time after unroll
        uint4 af = pack8(a0[s], a1[s]);
        uint4 bf = pack8(b0[s], b1[s]);
        if (c + 2 < NCH) {                   // depth-2 prefetch
            const float* qa = pa + (size_t)(c + 2) * 16;
            const float* qw = pw + (size_t)(c + 2) * 16;
            a0[s] = *(const float4*)qa; a1[s] = *(const float4*)(qa + 4);
            b0[s] = *(const float4*)qw; b1[s] = *(const float4*)(qw + 4);
        }
        acc = __builtin_amdgcn_mfma_f32_32x32x16_bf16(
            *(short8*)&af, *(short8*)&bf, acc, 0, 0, 0);
    }

    // cross-wave K reduction, parallel tail
    #pragma unroll
    for (int q = 0; q < 16; ++q) redf[w * 16 + q][lane] = acc[q];
    __syncthreads();

    // C/D layout: col=lane&31, row=(q&3)+8*(q>>2)+4*kh; q=4w+i -> row=i+8w+4kh
    const int ccol = col0 + m;
    const float bv = bias[ccol];
    float* cb = C + (size_t)(row0 + 8 * w + 4 * kh) * N + ccol;
    #pragma unroll
    for (int i = 0; i < 4; ++i) {
        const int q = 4 * w + i;
        float s2 = redf[q][lane] + redf[16 + q][lane]
                 + redf[32 + q][lane] + redf[48 + q][lane];
        cb[(size_t)i * N] = s2 + bv;         // 128B coalesced store
    }
}

// fused c & t: blocks 0..511 -> c (K=768, 12 chunks/wave), 512..1023 -> t (8)
__global__ __launch_bounds__(256) void gemm_ct_k(
    const float* __restrict__ combin, const float* __restrict__ W2,
    const float* __restrict__ b2, float* __restrict__ c_emb,
    const float* __restrict__ s_emb, const float* __restrict__ W1,
    const float* __restrict__ b1, float* __restrict__ t_emb)
{
    __shared__ float redf[64][64];   // 16 KB
    int id = blockIdx.x;
    if (id < 512) {
        gemm32_f32<12>(combin, W2, b2, c_emb, HID, IN_D,
                       (id >> 4) * 32, (id & 15) * 32, redf);
    } else {
        id -= 512;
        gemm32_f32<8>(s_emb, W1, b1, t_emb, HID, HID,
                      (id >> 4) * 32, (id & 15) * 32, redf);
    }
}

// K2: fused Taylor-attention + out-GEMM.
// 256 blocks = 32 row-tiles x 8 col-tiles; 512 threads (8 waves).
__global__ __launch_bounds__(512) void attn_out_k(
    const float* __restrict__ c_emb, const float* __restrict__ t_emb,
    const float* __restrict__ s_emb, const float* __restrict__ W3,
    const float* __restrict__ b3, float* __restrict__ out)
{
    __shared__ uint4 o2s[32 * 64];    // 32 KB: swizzled o2 bf16; later redf alias
    __shared__ float mom[32][2 * NK]; // 2 KB, pre-scaled by 1/k!

    const int tid  = threadIdx.x;
    const int w    = tid >> 6;
    const int lane = tid & 63;
    const int row0 = (blockIdx.x >> 3) * 32;
    const int col0 = (blockIdx.x & 7) * 32;

    const float invf[NK] = {1.f, 1.f, 0.5f, 1.f / 6.f, 1.f / 24.f,
                            1.f / 120.f, 1.f / 720.f, 1.f / 5040.f};

    // ---- Phase A1: moments. wave w owns rows 4w..4w+3 ----
    #pragma unroll
    for (int r4 = 0; r4 < 4; ++r4) {
        const int r = w * 4 + r4;
        const float* tp = t_emb + (size_t)(row0 + r) * HID + lane * 8;
        const float* vp = s_emb + (size_t)(row0 + r) * HID + lane * 8;
        float4 t0 = *(const float4*)tp, t1 = *(const float4*)(tp + 4);
        float4 v0 = *(const float4*)vp, v1 = *(const float4*)(vp + 4);
        const float te[8] = {t0.x, t0.y, t0.z, t0.w, t1.x, t1.y, t1.z, t1.w};
        const float ve[8] = {v0.x, v0.y, v0.z, v0.w, v1.x, v1.y, v1.z, v1.w};
        float p[NK] = {}, mm[NK] = {};
        #pragma unroll
        for (int e = 0; e < 8; ++e) {
            float tp2 = 1.f;
            #pragma unroll
            for (int k = 0; k < NK; ++k) {
                p[k] += tp2;
                mm[k] = fmaf(tp2, ve[e], mm[k]);
                tp2 *= te[e];
            }
        }
        #pragma unroll
        for (int off = 1; off < 64; off <<= 1) {
            #pragma unroll
            for (int k = 0; k < NK; ++k) {
                p[k]  += __shfl_xor(p[k], off);
                mm[k] += __shfl_xor(mm[k], off);
            }
        }
        if (lane == 0) {
            #pragma unroll
            for (int k = 0; k < NK; ++k) {
                mom[r][k]      = p[k]  * invf[k];
                mom[r][NK + k] = mm[k] * invf[k];
            }
        }
    }
    __syncthreads();

    // ---- Phase A2: Horner -> o2s (bf16, XOR-swizzled units) ----
    {
        const float scale = 0.04419417382415922f;  // 1/sqrt(512)
        const int hr = tid >> 4;       // row 0..31
        const int ub = tid & 15;       // base unit
        float cp[NK], cm[NK];
        #pragma unroll
        for (int k = 0; k < NK; ++k) { // broadcast LDS reads (free)
            cp[k] = mom[hr][k];
            cm[k] = mom[hr][NK + k];
        }
        #pragma unroll
        for (int j = 0; j < 4; ++j) {
            const int u = ub + 16 * j;                 // unit = 8 cols
            const float* cptr = c_emb + (size_t)(row0 + hr) * HID + u * 8;
            float4 c0 = *(const float4*)cptr, c1 = *(const float4*)(cptr + 4);
            const float ce[8] = {c0.x, c0.y, c0.z, c0.w, c1.x, c1.y, c1.z, c1.w};
            float rr8[8];
            #pragma unroll
            for (int e = 0; e < 8; ++e) {
                const float a = scale * ce[e];
                float n = cm[NK - 1], d = cp[NK - 1];
                #pragma unroll
                for (int k = NK - 2; k >= 0; --k) {
                    n = fmaf(n, a, cm[k]);
                    d = fmaf(d, a, cp[k]);
                }
                float rv = n * __builtin_amdgcn_rcpf(d);
                rr8[e] = rv > 0.f ? rv : 0.f;
            }
            uint4 pk;
            pk.x = pack_bf16(rr8[0], rr8[1]);
            pk.y = pack_bf16(rr8[2], rr8[3]);
            pk.z = pack_bf16(rr8[4], rr8[5]);
            pk.w = pack_bf16(rr8[6], rr8[7]);
            o2s[hr * 64 + (u ^ (hr & 7))] = pk;        // swizzled store
        }
    }
    __syncthreads();

    // ---- Phase B: out tile 32x32, K=512, 8-wave K-split (64 each) ----
    const int m  = lane & 31;
    const int kh = lane >> 5;
    const float* pw = W3 + (size_t)(col0 + m) * HID + w * 64 + kh * 8;

    floatx16 acc = {};
    #pragma unroll
    for (int cc = 0; cc < 4; ++cc) {
        const int u = w * 8 + cc * 2 + kh;
        uint4 af = o2s[m * 64 + (u ^ (m & 7))];        // swizzled ds_read_b128
        float4 u0 = *(const float4*)(pw + cc * 16);
        float4 u1 = *(const float4*)(pw + cc * 16 + 4);
        uint4 bf = pack8(u0, u1);
        acc = __builtin_amdgcn_mfma_f32_32x32x16_bf16(
            *(short8*)&af, *(short8*)&bf, acc, 0, 0, 0);
    }
    __syncthreads();                   // all o2s reads done -> safe to alias
    float* redf = (float*)o2s;         // 32 KB alias: [8 waves][16 q][64 lanes]
    #pragma unroll
    for (int q = 0; q < 16; ++q) redf[(w * 16 + q) * 64 + lane] = acc[q];
    __syncthreads();

    // wave w reduces q = 2w, 2w+1 over 8 partials; coalesced stores
    const float bv = b3[col0 + m];
    #pragma unroll
    for (int i = 0; i < 2; ++i) {
        const int q = 2 * w + i;
        float s = 0.f;
        #pragma unroll
        for (int ww = 0; ww < 8; ++ww) s += redf[(ww * 16 + q) * 64 + lane];
        const int rr = (q & 3) + 8 * (q >> 2) + 4 * kh;
        out[(size_t)(row0 + rr) * OUT_D + col0 + m] = s + bv;
    }
}

extern "C" void kernel_launch(void* const* d_in, const int* in_sizes, int n_in,
                              void* d_out, int out_size, void* d_ws, size_t ws_size,
                              hipStream_t stream)
{
    const float* combin = (const float*)d_in[0];
    const float* s_emb  = (const float*)d_in[1];
    const float* W1     = (const float*)d_in[2];
    const float* b1     = (const float*)d_in[3];
    const float* W2     = (const float*)d_in[4];
    const float* b2     = (const float*)d_in[5];
    const float* W3     = (const float*)d_in[6];
    const float* b3     = (const float*)d_in[7];
    float* out = (float*)d_out;

    float* ws = (float*)d_ws;
    float* c_emb = ws;                            // [B, HID] fp32
    float* t_emb = ws + (size_t)B_SZ * HID;       // [B, HID] fp32

    gemm_ct_k<<<1024, 256, 0, stream>>>(combin, W2, b2, c_emb,
                                        s_emb, W1, b1, t_emb);
    attn_out_k<<<256, 512, 0, stream>>>(c_emb, t_emb, s_emb, W3, b3, out);
}

// Round 4
// 104.907 us; speedup vs baseline: 1.0214x; 1.0214x over previous
//
#include <hip/hip_runtime.h>
#include <hip/hip_bf16.h>

// B=1024, IN=768, HID=512, OUT=256. Two dispatches:
//  K1 gemm_ct : blocks 0..511  -> c = combin@W2^T+b2 (K=768) -> c_emb global
//               blocks 512..1023 -> t = s_emb@W1^T+b1 (K=512) kept in REGISTERS;
//               epilogue computes per-colblock PARTIAL Taylor moments
//               (p_k = sum t^k, m_k = sum t^k*v, k=0..7) via half-wave
//               shfl butterfly and slot-writes mom_part[cb][row][16].
//               t is never materialized. No atomics (slot-owned writes),
//               so the poisoned workspace needs no zero-init.
//  K2 attn_out: 256 blocks x 512 thr (32-row x 32-col out tiles):
//               sum 16 moment partials -> Horner softmax-ratio + relu ->
//               o2 bf16 in XOR-swizzled LDS -> 32x32 MFMA vs W3 (8-wave
//               K-split) -> out. (r3-verified code paths, minus the
//               redundant in-kernel moment reduction that made r3 slow.)

#define B_SZ 1024
#define HID 512
#define IN_D 768
#define OUT_D 256
#define NK 8

typedef float floatx16 __attribute__((ext_vector_type(16)));
typedef short short8  __attribute__((ext_vector_type(8)));

// round-half-up fp32->bf16 pair pack (low16 = a, high16 = b)
__device__ __forceinline__ unsigned pack_bf16(float a, float b) {
    unsigned ua = __float_as_uint(a) + 0x8000u;
    unsigned ub = __float_as_uint(b) + 0x8000u;
    return __builtin_amdgcn_perm(ub, ua, 0x07060302);
}
__device__ __forceinline__ uint4 pack8(float4 lo, float4 hi) {
    uint4 v;
    v.x = pack_bf16(lo.x, lo.y); v.y = pack_bf16(lo.z, lo.w);
    v.z = pack_bf16(hi.x, hi.y); v.w = pack_bf16(hi.z, hi.w);
    return v;
}

// K-loop for one wave's K-slice: NCH 16-wide chunks, direct global fragment
// loads (lane m=lane&31 -> row, kh=lane>>5 -> 8-float half), depth-1 prefetch.
template<int NCH>
__device__ __forceinline__ floatx16 kloop_f32(
    const float* __restrict__ pa, const float* __restrict__ pw)
{
    float4 a0 = *(const float4*)pa, a1 = *(const float4*)(pa + 4);
    float4 b0 = *(const float4*)pw, b1 = *(const float4*)(pw + 4);
    floatx16 acc = {};
    #pragma unroll
    for (int c = 0; c < NCH; ++c) {
        uint4 af = pack8(a0, a1);
        uint4 bf = pack8(b0, b1);
        if (c + 1 < NCH) {
            pa += 16; pw += 16;
            a0 = *(const float4*)pa; a1 = *(const float4*)(pa + 4);
            b0 = *(const float4*)pw; b1 = *(const float4*)(pw + 4);
        }
        acc = __builtin_amdgcn_mfma_f32_32x32x16_bf16(
            *(short8*)&af, *(short8*)&bf, acc, 0, 0, 0);
    }
    return acc;
}

// K1: fused c-GEMM / t-GEMM+moments. 1024 blocks x 256 thr.
__global__ __launch_bounds__(256) void gemm_ct_k(
    const float* __restrict__ combin, const float* __restrict__ W2,
    const float* __restrict__ b2, float* __restrict__ c_emb,
    const float* __restrict__ s_emb, const float* __restrict__ W1,
    const float* __restrict__ b1, float* __restrict__ mom_part)
{
    __shared__ float redf[64][64];   // 16 KB cross-wave K-reduce
    const int tid  = threadIdx.x;
    const int w    = tid >> 6;
    const int lane = tid & 63;
    const int m    = lane & 31;
    const int kh   = lane >> 5;

    int id = blockIdx.x;
    if (id < 512) {
        // ---- c-tile: rows 32, cols 32, K=768 (12 chunks/wave) ----
        const int row0 = (id >> 4) * 32, col0 = (id & 15) * 32;
        const int k0 = w * 12 * 16 + kh * 8;
        floatx16 acc = kloop_f32<12>(
            combin + (size_t)(row0 + m) * IN_D + k0,
            W2     + (size_t)(col0 + m) * IN_D + k0);

        #pragma unroll
        for (int q = 0; q < 16; ++q) redf[w * 16 + q][lane] = acc[q];
        __syncthreads();

        // C/D: col=lane&31, row=(q&3)+8*(q>>2)+4*kh; q=4w+i -> row=i+8w+4kh
        const float bv = b2[col0 + m];
        float* cbp = c_emb + (size_t)(row0 + 8 * w + 4 * kh) * HID + col0 + m;
        #pragma unroll
        for (int i = 0; i < 4; ++i) {
            const int q = 4 * w + i;
            float s = redf[q][lane] + redf[16 + q][lane]
                    + redf[32 + q][lane] + redf[48 + q][lane];
            cbp[(size_t)i * HID] = s + bv;   // 128B coalesced
        }
    } else {
        // ---- t-tile: rows 32, t-cols 32, K=512 (8 chunks/wave) ----
        id -= 512;
        const int row0 = (id >> 4) * 32, col0 = (id & 15) * 32;
        const int cb   = id & 15;
        const int k0 = w * 8 * 16 + kh * 8;
        floatx16 acc = kloop_f32<8>(
            s_emb + (size_t)(row0 + m) * HID + k0,
            W1    + (size_t)(col0 + m) * HID + k0);

        #pragma unroll
        for (int q = 0; q < 16; ++q) redf[w * 16 + q][lane] = acc[q];
        __syncthreads();

        // Per-lane final t at (row 8w+4kh+i, col col0+m); fold in bias,
        // then partial moments over this block's 32 cols.
        const float bv = b1[col0 + m];
        #pragma unroll
        for (int i = 0; i < 4; ++i) {
            const int q = 4 * w + i;
            float tv = redf[q][lane] + redf[16 + q][lane]
                     + redf[32 + q][lane] + redf[48 + q][lane] + bv;
            const int rloc = 8 * w + 4 * kh + i;
            // v = s_emb[row][col]; half-wave lanes read 32 consecutive cols
            const float v = s_emb[(size_t)(row0 + rloc) * HID + col0 + m];

            float val[2 * NK];
            float tp = 1.f;
            #pragma unroll
            for (int k = 0; k < NK; ++k) {
                val[k]      = tp;          // p_k partial
                val[NK + k] = tp * v;      // m_k partial
                tp *= tv;
            }
            // reduce over the 32 cols held by this half-wave
            #pragma unroll
            for (int off = 1; off < 32; off <<= 1) {
                #pragma unroll
                for (int k2 = 0; k2 < 2 * NK; ++k2)
                    val[k2] += __shfl_xor(val[k2], off);
            }
            // slot write: mom_part[cb][row][k2]; lane m==k2 writes (static k2)
            float* mp = mom_part + ((size_t)(cb << 10) + row0 + rloc) * 16;
            #pragma unroll
            for (int k2 = 0; k2 < 2 * NK; ++k2)
                if (m == k2) mp[k2] = val[k2];
        }
    }
}

// K2: moment-sum + Horner + out-GEMM. 256 blocks (32 rows x 32 cols), 512 thr.
__global__ __launch_bounds__(512) void attn_out_k(
    const float* __restrict__ c_emb, const float* __restrict__ mom_part,
    const float* __restrict__ W3, const float* __restrict__ b3,
    float* __restrict__ out)
{
    __shared__ uint4 o2s[32 * 64];    // 32 KB swizzled o2 bf16; later redf alias
    __shared__ float mom[32][2 * NK]; // 2 KB raw moment sums

    const int tid  = threadIdx.x;
    const int w    = tid >> 6;
    const int lane = tid & 63;
    const int row0 = (blockIdx.x >> 3) * 32;
    const int col0 = (blockIdx.x & 7) * 32;

    // ---- A0: sum the 16 per-colblock partials ----
    {
        const int row = tid >> 4, k = tid & 15;   // 512 thr = 32 rows x 16 k
        const float* mp = mom_part + (size_t)(row0 + row) * 16 + k;
        float s = 0.f;
        #pragma unroll
        for (int cbk = 0; cbk < 16; ++cbk)
            s += mp[(size_t)cbk * (1024 * 16)];
        mom[row][k] = s;
    }
    __syncthreads();

    // ---- A2: Horner -> o2s (bf16, XOR-swizzled 16B units) ----
    {
        const float invf[NK] = {1.f, 1.f, 0.5f, 1.f / 6.f, 1.f / 24.f,
                                1.f / 120.f, 1.f / 720.f, 1.f / 5040.f};
        const float scale = 0.04419417382415922f;  // 1/sqrt(512)
        const int hr = tid >> 4;       // row 0..31
        const int ub = tid & 15;       // base unit
        float cp[NK], cm[NK];
        #pragma unroll
        for (int k = 0; k < NK; ++k) {
            cp[k] = mom[hr][k]      * invf[k];
            cm[k] = mom[hr][NK + k] * invf[k];
        }
        #pragma unroll
        for (int j = 0; j < 4; ++j) {
            const int u = ub + 16 * j;                 // unit = 8 cols
            const float* cptr = c_emb + (size_t)(row0 + hr) * HID + u * 8;
            float4 c0 = *(const float4*)cptr, c1 = *(const float4*)(cptr + 4);
            const float ce[8] = {c0.x, c0.y, c0.z, c0.w, c1.x, c1.y, c1.z, c1.w};
            float rr8[8];
            #pragma unroll
            for (int e = 0; e < 8; ++e) {
                const float a = scale * ce[e];
                float n = cm[NK - 1], d = cp[NK - 1];
                #pragma unroll
                for (int k = NK - 2; k >= 0; --k) {
                    n = fmaf(n, a, cm[k]);
                    d = fmaf(d, a, cp[k]);
                }
                float rv = n * __builtin_amdgcn_rcpf(d);
                rr8[e] = rv > 0.f ? rv : 0.f;
            }
            uint4 pk;
            pk.x = pack_bf16(rr8[0], rr8[1]);
            pk.y = pack_bf16(rr8[2], rr8[3]);
            pk.z = pack_bf16(rr8[4], rr8[5]);
            pk.w = pack_bf16(rr8[6], rr8[7]);
            o2s[hr * 64 + (u ^ (hr & 7))] = pk;        // swizzled store
        }
    }
    __syncthreads();

    // ---- B: out tile 32x32, K=512, 8-wave K-split (64 each) ----
    const int m  = lane & 31;
    const int kh = lane >> 5;
    const float* pw = W3 + (size_t)(col0 + m) * HID + w * 64 + kh * 8;

    floatx16 acc = {};
    #pragma unroll
    for (int cc = 0; cc < 4; ++cc) {
        const int u = w * 8 + cc * 2 + kh;
        uint4 af = o2s[m * 64 + (u ^ (m & 7))];        // swizzled ds_read_b128
        float4 u0 = *(const float4*)(pw + cc * 16);
        float4 u1 = *(const float4*)(pw + cc * 16 + 4);
        uint4 bf = pack8(u0, u1);
        acc = __builtin_amdgcn_mfma_f32_32x32x16_bf16(
            *(short8*)&af, *(short8*)&bf, acc, 0, 0, 0);
    }
    __syncthreads();                   // all o2s reads done -> safe to alias
    float* redf = (float*)o2s;         // alias: [8 waves][16 q][64 lanes]
    #pragma unroll
    for (int q = 0; q < 16; ++q) redf[(w * 16 + q) * 64 + lane] = acc[q];
    __syncthreads();

    // wave w reduces q = 2w, 2w+1 over 8 partials; coalesced stores
    const float bv = b3[col0 + m];
    #pragma unroll
    for (int i = 0; i < 2; ++i) {
        const int q = 2 * w + i;
        float s = 0.f;
        #pragma unroll
        for (int ww = 0; ww < 8; ++ww) s += redf[(ww * 16 + q) * 64 + lane];
        const int rr = (q & 3) + 8 * (q >> 2) + 4 * kh;
        out[(size_t)(row0 + rr) * OUT_D + col0 + m] = s + bv;
    }
}

extern "C" void kernel_launch(void* const* d_in, const int* in_sizes, int n_in,
                              void* d_out, int out_size, void* d_ws, size_t ws_size,
                              hipStream_t stream)
{
    const float* combin = (const float*)d_in[0];
    const float* s_emb  = (const float*)d_in[1];
    const float* W1     = (const float*)d_in[2];
    const float* b1     = (const float*)d_in[3];
    const float* W2     = (const float*)d_in[4];
    const float* b2     = (const float*)d_in[5];
    const float* W3     = (const float*)d_in[6];
    const float* b3     = (const float*)d_in[7];
    float* out = (float*)d_out;

    float* ws = (float*)d_ws;
    float* c_emb    = ws;                          // [1024][512] f32 = 2 MB
    float* mom_part = ws + (size_t)B_SZ * HID;     // [16][1024][16] f32 = 1 MB

    gemm_ct_k<<<1024, 256, 0, stream>>>(combin, W2, b2, c_emb,
                                        s_emb, W1, b1, mom_part);
    attn_out_k<<<256, 512, 0, stream>>>(c_emb, mom_part, W3, b3, out);
}